// Round 3
// baseline (967.944 us; speedup 1.0000x reference)
//
#include <hip/hip_runtime.h>
#include <hip/hip_bf16.h>
#include <cmath>

#define AS_GLOBAL __attribute__((address_space(1)))
#define AS_LDS    __attribute__((address_space(3)))

typedef __attribute__((ext_vector_type(8))) short bf16x8;
typedef __attribute__((ext_vector_type(4))) float f32x4;
typedef unsigned short u16;

__device__ __forceinline__ u16 f2bf(float f) {
  union { __hip_bfloat16 h; u16 u; } cv;
  cv.h = __float2bfloat16(f);
  return cv.u;
}
__device__ __forceinline__ float bf2f(u16 u) {
  union { unsigned u32; float f; } v;
  v.u32 = ((unsigned)u) << 16;
  return v.f;
}

// ---------------------------------------------------------------- prep kernels

__global__ void k_f32_to_bf16(const float* __restrict__ in, u16* __restrict__ out, int n4) {
  int i = blockIdx.x * 256 + threadIdx.x;
  if (i >= n4) return;
  float4 v = ((const float4*)in)[i];
  ushort4 o;
  o.x = f2bf(v.x); o.y = f2bf(v.y); o.z = f2bf(v.z); o.w = f2bf(v.w);
  ((ushort4*)out)[i] = o;
}

// out[n][k] = bf16(in[k][n]), 1024x1024; 5 weights in one dispatch (blockIdx.z)
__global__ void k_transpose_w5(const float* __restrict__ s0, const float* __restrict__ s1,
                               const float* __restrict__ s2, const float* __restrict__ s3,
                               const float* __restrict__ s4, u16* __restrict__ dbase) {
  __shared__ float tile[32][33];
  const float* in;
  switch (blockIdx.z) {
    case 0: in = s0; break;
    case 1: in = s1; break;
    case 2: in = s2; break;
    case 3: in = s3; break;
    default: in = s4; break;
  }
  u16* out = dbase + (size_t)blockIdx.z * 1024 * 1024;
  const int tx = threadIdx.x & 31;
  const int ty = threadIdx.x >> 5;  // 0..7
  const int x0 = blockIdx.x * 32, y0 = blockIdx.y * 32;
  #pragma unroll
  for (int i = 0; i < 32; i += 8)
    tile[ty + i][tx] = in[(size_t)(y0 + ty + i) * 1024 + x0 + tx];
  __syncthreads();
  #pragma unroll
  for (int i = 0; i < 32; i += 8)
    out[(size_t)(x0 + ty + i) * 1024 + y0 + tx] = f2bf(tile[tx][ty + i]);
}

// scale vector for fused QKV epilogue: [0,1024) Q_SCALE*softplus(pds), [1024,2048) KS, [2048,3072) 1
__global__ void k_qscale3(const float* __restrict__ pds, float* __restrict__ qs,
                          float qscale_c, float ks) {
  int n = blockIdx.x * 256 + threadIdx.x;  // 0..3071
  float v;
  if (n < 1024) v = qscale_c * log1pf(expf(pds[n & 127]));
  else if (n < 2048) v = ks;
  else v = 1.0f;
  qs[n] = v;
}

// relkb[p][n] = bf16( sum_k pos[p][k] * Wrel[k][n] )  (wrt = Wrel^T bf16)
__global__ void k_relk(const float* __restrict__ pos, const u16* __restrict__ wrt,
                       u16* __restrict__ relkb) {
  __shared__ float prow[1024];
  const int tid = threadIdx.x;
  const int p = blockIdx.y;
  ((float4*)prow)[tid] = ((const float4*)(pos + (size_t)p * 1024))[tid];
  __syncthreads();
  int nn = blockIdx.x * 256 + tid;
  const u16* wr = wrt + (size_t)nn * 1024;
  float acc = 0.f;
  for (int kk = 0; kk < 1024; kk += 8) {
    ushort4 u0 = *(const ushort4*)(wr + kk);
    ushort4 u1 = *(const ushort4*)(wr + kk + 4);
    acc += bf2f(u0.x) * prow[kk + 0] + bf2f(u0.y) * prow[kk + 1]
         + bf2f(u0.z) * prow[kk + 2] + bf2f(u0.w) * prow[kk + 3]
         + bf2f(u1.x) * prow[kk + 4] + bf2f(u1.y) * prow[kk + 5]
         + bf2f(u1.z) * prow[kk + 6] + bf2f(u1.w) * prow[kk + 7];
  }
  relkb[(size_t)p * 1024 + nn] = f2bf(acc);
}

// ---------------------------------------------------------------- GEMM (m97 structure)
// 1-D grid with XCD-resident-B swizzle: c=gid&7, t=gid>>3, x=c+8*(t%PX), y=t/PX.
// Each XCD owns PX B-column-panels (kept L2-resident); the PX same-y blocks in an
// XCD are dispatch-adjacent -> A stripe fetched ~once per XCD.
// KIND 0: fused QKV, N=3072 (cols 0-1023 -> q bf16 rm, 1024-2047 -> k bf16 rm,
//         2048-3071 -> v bf16 TRANSPOSED ovt[col*M+row]); scale_vec[3072].
// KIND 1: fp32 row-major out (N=1024), unit scale.
template <int KIND>
__global__ __launch_bounds__(256) void k_gemm_bt(
    const u16* __restrict__ A, const u16* __restrict__ Bt,
    u16* __restrict__ oq, u16* __restrict__ ok, u16* __restrict__ ovt,
    float* __restrict__ ofp, const float* __restrict__ scale_vec,
    int M, int K, int PX) {
  __shared__ __align__(16) u16 As[128 * 32];
  __shared__ __align__(16) u16 Bs[128 * 32];
  const int gid = blockIdx.x;
  const int cid = gid & 7, t = gid >> 3;
  const int xb = cid + 8 * (t % PX);
  const int yb = t / PX;
  const int tid = threadIdx.x;
  const int wave = tid >> 6, lane = tid & 63;
  const int quad = lane >> 4, l16 = lane & 15;
  const int wm = wave >> 1, wn = wave & 1;
  const int m0 = yb * 128, n0 = xb * 128;

  f32x4 acc[4][4];
  #pragma unroll
  for (int i = 0; i < 4; ++i)
    #pragma unroll
    for (int j = 0; j < 4; ++j) {
      f32x4 z = {0.f, 0.f, 0.f, 0.f};
      acc[i][j] = z;
    }

  for (int k0 = 0; k0 < K; k0 += 32) {
    __syncthreads();
    #pragma unroll
    for (int i = 0; i < 2; ++i) {
      int cbase = i * 256 + wave * 64;
      int c = cbase + lane;
      const u16* ga = A + (size_t)(m0 + (c >> 2)) * K + (k0 + (c & 3) * 8);
      __builtin_amdgcn_global_load_lds((const AS_GLOBAL u16*)ga, (AS_LDS u16*)&As[cbase * 8], 16, 0, 0);
      const u16* gb = Bt + (size_t)(n0 + (c >> 2)) * K + (k0 + (c & 3) * 8);
      __builtin_amdgcn_global_load_lds((const AS_GLOBAL u16*)gb, (AS_LDS u16*)&Bs[cbase * 8], 16, 0, 0);
    }
    __syncthreads();

    bf16x8 af[4], bfr[4];
    #pragma unroll
    for (int mi = 0; mi < 4; ++mi)
      af[mi] = *(const bf16x8*)&As[(wm * 64 + mi * 16 + l16) * 32 + quad * 8];
    #pragma unroll
    for (int ni = 0; ni < 4; ++ni)
      bfr[ni] = *(const bf16x8*)&Bs[(wn * 64 + ni * 16 + l16) * 32 + quad * 8];
    #pragma unroll
    for (int mi = 0; mi < 4; ++mi)
      #pragma unroll
      for (int ni = 0; ni < 4; ++ni)
        acc[mi][ni] = __builtin_amdgcn_mfma_f32_16x16x32_bf16(af[mi], bfr[ni], acc[mi][ni], 0, 0, 0);
  }

  if (KIND == 0) {
    const int region = xb >> 3;  // 0=q, 1=k, 2=v (x in [0,24))
    if (region == 2) {
      // transposed bf16 store: ovt[(col-2048)*M + row], rows consecutive -> ushort4
      #pragma unroll
      for (int ni = 0; ni < 4; ++ni) {
        int col = n0 + wn * 64 + ni * 16 + l16 - 2048;
        #pragma unroll
        for (int mi = 0; mi < 4; ++mi) {
          int row = m0 + wm * 64 + mi * 16 + quad * 4;
          ushort4 o;
          o.x = f2bf(acc[mi][ni][0]);
          o.y = f2bf(acc[mi][ni][1]);
          o.z = f2bf(acc[mi][ni][2]);
          o.w = f2bf(acc[mi][ni][3]);
          *(ushort4*)&ovt[(size_t)col * M + row] = o;
        }
      }
    } else {
      u16* dst = region ? ok : oq;
      #pragma unroll
      for (int ni = 0; ni < 4; ++ni) {
        int col = n0 + wn * 64 + ni * 16 + l16;
        float cs = scale_vec[col];
        int colr = col & 1023;
        #pragma unroll
        for (int mi = 0; mi < 4; ++mi) {
          int row = m0 + wm * 64 + mi * 16 + quad * 4;
          #pragma unroll
          for (int r = 0; r < 4; ++r)
            dst[(size_t)(row + r) * 1024 + colr] = f2bf(acc[mi][ni][r] * cs);
        }
      }
    }
  } else {
    #pragma unroll
    for (int ni = 0; ni < 4; ++ni) {
      int col = n0 + wn * 64 + ni * 16 + l16;
      #pragma unroll
      for (int mi = 0; mi < 4; ++mi) {
        int row = m0 + wm * 64 + mi * 16 + quad * 4;
        #pragma unroll
        for (int r = 0; r < 4; ++r)
          ofp[(size_t)(row + r) * 1024 + col] = acc[mi][ni][r];
      }
    }
  }
}

// ---------------------------------------------------------------- attention (MFMA, 1 wave per unit)
// unit = (b, n, h); CHUNK=12, PAST=12, CTX=24, P=25, D=128, SOFTCAP=50.
// q,k: [b*2400+s][1024] bf16 rows.  vt: TRANSPOSED [col][38400] bf16 (col = h*128+d), +16 u16 front slack.
// relkb: [32][1024] bf16 (rows 25..31 garbage, never used in output).
// C-layout: col = l16, row = quad*4+reg.  A-layout: A[m=l16][k=quad*8+j].
__global__ __launch_bounds__(256) void k_attn_mfma(
    const u16* __restrict__ q, const u16* __restrict__ k, const u16* __restrict__ vt,
    const u16* __restrict__ relkb, u16* __restrict__ ctx) {
  __shared__ float bdm_s[4][400];     // per-wave [16][25] row-major (flat reindex target)
  __shared__ u16 attnb[4][16 * 32];   // per-wave P matrix, A-layout staging

  const int tid = threadIdx.x;
  const int w = tid >> 6, lane = tid & 63;
  const int l16 = lane & 15, quad = lane >> 4;
  const int id = blockIdx.x * 4 + w;          // 0..25599
  const int b = id / 1600;
  const int rr = id % 1600;
  const int n = rr >> 3, h = rr & 7;
  const int s0 = n * 12;
  const size_t rowbase = (size_t)b * 2400;

  // ---- Q a-frags (m = l16 = q-row, k-chunks c: k = 32c + quad*8 + j)
  bf16x8 qf[4];
  {
    int sq = s0 + l16;
    if (sq > 2399) sq = 2399;  // pad q-rows read real data; outputs never stored
    const u16* qp = q + ((rowbase + sq) * 1024 + (size_t)h * 128 + quad * 8);
    #pragma unroll
    for (int c = 0; c < 4; ++c) qf[c] = *(const bf16x8*)(qp + 32 * c);
  }

  // ---- bd = Q @ rel_k^T  (2 p-tiles), store to LDS [16][25] for flat reindex
  #pragma unroll
  for (int pt = 0; pt < 2; ++pt) {
    int p = pt * 16 + l16;
    const u16* rp = relkb + ((size_t)p * 1024 + (size_t)h * 128 + quad * 8);
    f32x4 acc = {0.f, 0.f, 0.f, 0.f};
    #pragma unroll
    for (int c = 0; c < 4; ++c)
      acc = __builtin_amdgcn_mfma_f32_16x16x32_bf16(qf[c], *(const bf16x8*)(rp + 32 * c), acc, 0, 0, 0);
    if (p < 25) {
      #pragma unroll
      for (int r = 0; r < 4; ++r)
        bdm_s[w][(quad * 4 + r) * 25 + p] = acc[r];
    }
  }
  __threadfence_block();  // LDS write->read ordering within wave

  // ---- ac = Q @ K^T (2 t-tiles) + combine with shifted bd + softcap
  float l0[4], l1[4];
  #pragma unroll
  for (int kt = 0; kt < 2; ++kt) {
    int t = kt * 16 + l16;
    int sk = s0 - 12 + t;
    bool kvalid = ((unsigned)sk < 2400u);
    int ska = kvalid ? sk : 0;
    const u16* kp = k + ((rowbase + ska) * 1024 + (size_t)h * 128 + quad * 8);
    short km = kvalid ? (short)0xFFFF : (short)0;
    bf16x8 kmv = {km, km, km, km, km, km, km, km};
    f32x4 acc = {0.f, 0.f, 0.f, 0.f};
    #pragma unroll
    for (int c = 0; c < 4; ++c) {
      bf16x8 kf = *(const bf16x8*)(kp + 32 * c);
      kf &= kmv;  // zero-padded context rows: ac = 0, bd still enters softmax
      acc = __builtin_amdgcn_mfma_f32_16x16x32_bf16(qf[c], kf, acc, 0, 0, 0);
    }
    #pragma unroll
    for (int r = 0; r < 4; ++r) {
      float bd = bdm_s[w][(quad * 4 + r) * 24 + t];  // rel-shift = flat reindex
      float lg = tanhf((acc[r] + bd) * (1.0f / 50.0f)) * 50.0f;
      if (kt == 1 && l16 >= 8) lg = -INFINITY;  // t >= 24: outside CTX
      if (kt) l1[r] = lg; else l0[r] = lg;
    }
  }

  // ---- softmax over t (row q = quad*4+r lives in a 16-lane group)
  float at0[4], at1[4];
  #pragma unroll
  for (int r = 0; r < 4; ++r) {
    float m = fmaxf(l0[r], l1[r]);
    #pragma unroll
    for (int s = 1; s < 16; s <<= 1) m = fmaxf(m, __shfl_xor(m, s, 64));
    float e0 = __expf(l0[r] - m), e1 = __expf(l1[r] - m);
    float sum = e0 + e1;
    #pragma unroll
    for (int s = 1; s < 16; s <<= 1) sum += __shfl_xor(sum, s, 64);
    float inv = 1.0f / sum;
    at0[r] = e0 * inv;
    at1[r] = e1 * inv;
  }

  // ---- P: C-layout -> A-layout via LDS (bf16)
  #pragma unroll
  for (int r = 0; r < 4; ++r) {
    attnb[w][(quad * 4 + r) * 32 + l16] = f2bf(at0[r]);
    attnb[w][(quad * 4 + r) * 32 + 16 + l16] = f2bf(at1[r]);
  }
  __threadfence_block();
  bf16x8 af = *(const bf16x8*)&attnb[w][l16 * 32 + quad * 8];

  // ---- PV: 8 d-tiles, B-frag = V^T[d][t] contiguous in vt; mask invalid s elements
  int slo = s0 - 12 + quad * 8;
  bf16x8 vmsk;
  #pragma unroll
  for (int j = 0; j < 8; ++j)
    vmsk[j] = ((unsigned)(slo + j) < 2400u) ? (short)0xFFFF : (short)0;

  f32x4 oacc[8];
  #pragma unroll
  for (int dt = 0; dt < 8; ++dt) {
    int col = h * 128 + dt * 16 + l16;
    const u16* vp = vt + ((size_t)col * 38400 + (long)(rowbase + s0 - 12 + quad * 8));
    ushort4 va = *(const ushort4*)vp;
    ushort4 vb = *(const ushort4*)(vp + 4);
    bf16x8 vf = {(short)va.x, (short)va.y, (short)va.z, (short)va.w,
                 (short)vb.x, (short)vb.y, (short)vb.z, (short)vb.w};
    vf &= vmsk;
    f32x4 z = {0.f, 0.f, 0.f, 0.f};
    oacc[dt] = __builtin_amdgcn_mfma_f32_16x16x32_bf16(af, vf, z, 0, 0, 0);
  }

  // ---- store O (rows q = quad*4+r, only q<12 valid -> quads 0..2)
  if (quad < 3) {
    #pragma unroll
    for (int dt = 0; dt < 8; ++dt) {
      int col = h * 128 + dt * 16 + l16;
      #pragma unroll
      for (int r = 0; r < 4; ++r) {
        int qi = quad * 4 + r;
        ctx[(rowbase + s0 + qi) * 1024 + col] = f2bf(oacc[dt][r]);
      }
    }
  }
}

// ---------------------------------------------------------------- launch

extern "C" void kernel_launch(void* const* d_in, const int* in_sizes, int n_in,
                              void* d_out, int out_size, void* d_ws, size_t ws_size,
                              hipStream_t stream) {
  const float* x       = (const float*)d_in[0];  // [16,2400,1024]
  const float* pos_emb = (const float*)d_in[1];  // [25,1024]
  const float* Wq      = (const float*)d_in[2];
  const float* Wk      = (const float*)d_in[3];
  const float* Wv      = (const float*)d_in[4];
  const float* Wpost   = (const float*)d_in[5];
  const float* Wrel    = (const float*)d_in[6];
  const float* pds     = (const float*)d_in[7];  // [128]
  float* out = (float*)d_out;

  const int M = 38400, HS = 1024;           // M = B*S = 16*2400
  const size_t XE = (size_t)M * HS;

  // workspace layout (u16 units)
  u16* xbf = (u16*)d_ws;                 // XE; reused as ctx after QKV GEMM consumes it
  u16* qbf = xbf + XE;                   // XE
  u16* kbf = qbf + XE;                   // XE
  u16* vt_alloc = kbf + XE;              // XE + 64 (slack for boundary-masked loads)
  u16* vt = vt_alloc + 16;
  u16* wqt = vt_alloc + XE + 64;         // wqt,wkt,wvt consecutive = fused B [3072][1024]
  u16* wkt = wqt + (size_t)HS * HS;
  u16* wvt = wkt + (size_t)HS * HS;
  u16* wrt = wvt + (size_t)HS * HS;
  u16* wpt = wrt + (size_t)HS * HS;
  u16* relkb = wpt + (size_t)HS * HS;    // 32*1024 (rows 25..31 unwritten, harmless)
  float* qsc = (float*)(relkb + 32 * 1024);  // 3072 floats

  const double LN2 = 0.6931471805599453;
  const float QS = (float)((1.0 / sqrt(128.0)) / LN2);
  const float KS = (float)(log(1.0 + exp(1.0)) / LN2);

  // 1) x -> bf16
  k_f32_to_bf16<<<(int)(XE / 4 / 256), 256, 0, stream>>>(x, xbf, (int)(XE / 4));
  // 2) transpose 5 weights -> bf16 [n][k] (one dispatch)
  k_transpose_w5<<<dim3(32, 32, 5), 256, 0, stream>>>(Wq, Wk, Wv, Wrel, Wpost, wqt);
  // 3) fused epilogue scale vector [3072]
  k_qscale3<<<12, 256, 0, stream>>>(pds, qsc, QS, KS);
  // 4) rel_k = pos_emb @ Wrel -> bf16
  k_relk<<<dim3(4, 25), 256, 0, stream>>>(pos_emb, wrt, relkb);
  // 5) fused QKV projection: N=3072, grid 8*900 (PX=3: x = c+8*(t%3), y = t/3)
  k_gemm_bt<0><<<7200, 256, 0, stream>>>(xbf, wqt, qbf, kbf, vt, nullptr, qsc, M, HS, 3);
  // 6) attention -> ctx (reuses xbf region; stream-ordered after QKV reads)
  k_attn_mfma<<<25600 / 4, 256, 0, stream>>>(qbf, kbf, vt, relkb, xbf);
  // 7) out = ctx @ Wpost (fp32 out), N=1024, grid 8*300 (PX=1: x = c, y = t)
  k_gemm_bt<1><<<2400, 256, 0, stream>>>(xbf, wpt, nullptr, nullptr, nullptr, out, nullptr, M, HS, 1);
}